// Round 3
// baseline (728.248 us; speedup 1.0000x reference)
//
#include <hip/hip_runtime.h>

typedef unsigned int u32;
typedef unsigned short u16;
typedef __attribute__((ext_vector_type(8))) __bf16 bf16x8;
typedef __attribute__((ext_vector_type(4))) float f32x4;

typedef __attribute__((address_space(1))) void as1_void;
typedef __attribute__((address_space(3))) void as3_void;

__device__ __forceinline__ u16 f2bf(float f){
  u32 u = __builtin_bit_cast(u32, f);
  return (u16)((u + 0x7FFFu + ((u >> 16) & 1u)) >> 16);
}
__device__ __forceinline__ float bf2f(u16 h){
  u32 u = ((u32)h) << 16;
  return __builtin_bit_cast(float, u);
}

__device__ __forceinline__ void gload16(const void* g, void* l){
  __builtin_amdgcn_global_load_lds((as1_void*)(unsigned long long)g, (as3_void*)l, 16, 0, 0);
}
__device__ __forceinline__ bf16x8 ldfrag(const char* p){
  return __builtin_bit_cast(bf16x8, *(const uint4*)p);
}

// ---------- weight transpose-cast: out[n][k] = W[k][n] * scale (1024x1024) ----------
__global__ void wcast(const float* __restrict__ W, float scale, u16* __restrict__ out){
  __shared__ float t[32][33];
  int bx = blockIdx.x * 32, by = blockIdx.y * 32;
  int tx = threadIdx.x, ty = threadIdx.y;
  #pragma unroll
  for (int i = 0; i < 32; i += 8) t[ty + i][tx] = W[(size_t)(bx + ty + i) * 1024 + by + tx];
  __syncthreads();
  #pragma unroll
  for (int i = 0; i < 32; i += 8)
    out[(size_t)(by + ty + i) * 1024 + bx + tx] = f2bf(scale * t[tx][ty + i]);
}

// ---------- fp32 -> bf16 cast, 8 elems/thread ----------
__global__ __launch_bounds__(256) void castbf(const float* __restrict__ in, u16* __restrict__ out, int n8){
  int stride = gridDim.x * blockDim.x;
  for (int i = blockIdx.x * blockDim.x + threadIdx.x; i < n8; i += stride){
    const float4* p = (const float4*)(in + (size_t)i * 8);
    float4 f0 = p[0], f1 = p[1];
    union { uint4 u; u16 h[8]; } uu;
    uu.h[0]=f2bf(f0.x); uu.h[1]=f2bf(f0.y); uu.h[2]=f2bf(f0.z); uu.h[3]=f2bf(f0.w);
    uu.h[4]=f2bf(f1.x); uu.h[5]=f2bf(f1.y); uu.h[6]=f2bf(f1.z); uu.h[7]=f2bf(f1.w);
    ((uint4*)out)[i] = uu.u;
  }
}

// ---------- row softmax, in-place on bf16 S rows of length 2048 ----------
__global__ __launch_bounds__(256) void softmax_rows(u16* __restrict__ S){
  __shared__ float red[8];
  size_t row = blockIdx.x;
  uint4* p = (uint4*)(S + row * 2048);
  int tid = threadIdx.x;
  int lane = tid & 63, wave = tid >> 6;
  union { uint4 u4; u16 h[8]; } uu;
  uu.u4 = p[tid];
  float v[8];
  float m = -1e30f;
  #pragma unroll
  for (int j = 0; j < 8; j++){ v[j] = bf2f(uu.h[j]); m = fmaxf(m, v[j]); }
  #pragma unroll
  for (int o = 32; o; o >>= 1) m = fmaxf(m, __shfl_xor(m, o));
  if (lane == 0) red[wave] = m;
  __syncthreads();
  m = fmaxf(fmaxf(red[0], red[1]), fmaxf(red[2], red[3]));
  float s = 0.f;
  #pragma unroll
  for (int j = 0; j < 8; j++){ v[j] = __expf(v[j] - m); s += v[j]; }
  #pragma unroll
  for (int o = 32; o; o >>= 1) s += __shfl_xor(s, o);
  if (lane == 0) red[4 + wave] = s;
  __syncthreads();
  s = red[4] + red[5] + red[6] + red[7];
  float inv = 1.f / s;
  #pragma unroll
  for (int j = 0; j < 8; j++) uu.h[j] = f2bf(v[j] * inv);
  p[tid] = uu.u4;
}

// ---------- persistent 256x256 8-phase GEMM: C = A @ B^T (+col bias) ----------
// grid=256 blocks (1/CU), each walks TPB tiles with a FLAT step counter so the
// counted-vmcnt pipeline never drains at tile boundaries.

template<int MO, int N0>
__device__ __forceinline__ void phase_mfma(f32x4 (&acc)[8][4], bf16x8 (&a)[4][2], bf16x8 (&b)[4][2]){
  __builtin_amdgcn_s_setprio(1);
  #pragma unroll
  for (int ks = 0; ks < 2; ks++)
    #pragma unroll
    for (int mm = 0; mm < 4; mm++)
      #pragma unroll
      for (int nn = 0; nn < 2; nn++)
        acc[MO + mm][N0 + nn] = __builtin_amdgcn_mfma_f32_16x16x32_bf16(
            a[mm][ks], b[N0 + nn][ks], acc[MO + mm][N0 + nn], 0, 0, 0);
  __builtin_amdgcn_s_setprio(0);
}

template<int BIAS, int OUTF32>
__global__ __launch_bounds__(512, 2) void gemm8(
    const u16* __restrict__ A, const u16* __restrict__ B, void* __restrict__ C,
    const float* __restrict__ bias, float bscale, int NT,
    long long sA, long long sB, long long sC,
    int lda, int ldb, int ldc, int gx, int gxy, int TPB)
{
  __shared__ u16 sm[2][2][16384];   // [buf][A/B] 128 KiB
  char* smb = (char*)sm;

  int tid = threadIdx.x;
  int lane = tid & 63, wave = tid >> 6;
  int wr = wave >> 2, wc = wave & 3;
  int l15 = lane & 15, l4 = lane >> 4;

  int b = blockIdx.x;
  int lin0 = ((b & 7) * 32 + (b >> 3)) * TPB;   // XCD-chunked tile range

  // staging addressing: quarter i covers rows [i*64, i*64+64), 16B per lane
  int r = tid >> 3, cl = tid & 7;
  int ldsb = r * 128 + cl * 16;
  u32 aoff[4], boff[4];
  #pragma unroll
  for (int i = 0; i < 4; i++){
    int row = i * 64 + r;
    int ksw = (cl ^ (r & 7)) * 8;            // inverse-swizzled global k-chunk
    aoff[i] = (u32)(((u32)row * (u32)lda + (u32)ksw) * 2u);
    boff[i] = (u32)(((u32)row * (u32)ldb + (u32)ksw) * 2u);
  }
  // fragment-read addressing (swizzled)
  u32 ardo[2], brdo[2];
  #pragma unroll
  for (int ks = 0; ks < 2; ks++){
    u32 sw = (u32)(((ks * 4 + l4) ^ (l15 & 7)) * 16);
    ardo[ks] = (u32)(wr * 16384 + l15 * 128) + sw;
    brdo[ks] = (u32)(wc * 8192 + l15 * 128) + sw;
  }

  auto tcoord = [&](int lin, int& x, int& y, int& z){
    z = lin / gxy; int rem = lin - z * gxy; y = rem / gx; x = rem - y * gx;
  };
  auto abase = [&](int lin){ int x, y, z; tcoord(lin, x, y, z);
    return (const char*)(A + (long long)z * sA + (size_t)(x * 256) * lda); };
  auto bbase = [&](int lin){ int x, y, z; tcoord(lin, x, y, z);
    return (const char*)(B + (long long)z * sB + (size_t)(y * 256) * ldb); };

  // current-tile coords (epilogue)
  int tx, ty, tz;
  tcoord(lin0, tx, ty, tz);
  int row0 = tx * 256, col0 = ty * 256;
  long long zbC = tz;

  // bias preload (col bias only; all BIAS=1 calls have TPB<=2)
  float bc0[4], bc1[4];
  if (BIAS){
    int xx, yy, zz;
    tcoord(lin0, xx, yy, zz);
    int c0 = yy * 256 + wc * 64 + l15;
    #pragma unroll
    for (int n = 0; n < 4; n++) bc0[n] = bscale * bias[c0 + n * 16];
    tcoord(lin0 + (TPB > 1 ? 1 : 0), xx, yy, zz);
    c0 = yy * 256 + wc * 64 + l15;
    #pragma unroll
    for (int n = 0; n < 4; n++) bc1[n] = bscale * bias[c0 + n * 16];
  }

  // staging cursors: M -> tile of (s+1) [A_hi], P -> tile of (s+2) [A_lo + B]
  const char* AgM = abase(lin0);
  const char* AgP = AgM;
  const char* BgP = bbase(lin0);
  int km = 1, kp = 2, jm = 0, jp = 0, kk = 0, jj = 0;

#define STA(bse, i, kq, bb) gload16((bse) + aoff[i] + (size_t)(kq) * 128, smb + (bb) * 65536 + (i) * 8192 + ldsb)
#define STB(bse, i, kq, bb) gload16((bse) + boff[i] + (size_t)(kq) * 128, smb + (bb) * 65536 + 32768 + (i) * 8192 + ldsb)

  // prologue: step0 full (8), step1 minus A_hi (6)
  STA(AgM, 0, 0, 0); STA(AgM, 2, 0, 0);
  STB(BgP, 0, 0, 0); STB(BgP, 1, 0, 0); STB(BgP, 2, 0, 0); STB(BgP, 3, 0, 0);
  STA(AgM, 1, 0, 0); STA(AgM, 3, 0, 0);
  STA(AgM, 0, 1, 1); STA(AgM, 2, 1, 1);
  STB(BgP, 0, 1, 1); STB(BgP, 1, 1, 1); STB(BgP, 2, 1, 1); STB(BgP, 3, 1, 1);
  asm volatile("s_waitcnt vmcnt(6)" ::: "memory");
  __builtin_amdgcn_s_barrier();

  f32x4 acc[8][4] = {};
  bf16x8 a[4][2], bfr[4][2];
  int S = TPB * NT;

  for (int s = 0; s < S; s++){
    int cur = s & 1;
    const char* Ab = smb + cur * 65536;
    const char* Bb = Ab + 32768;
    bool st1 = (s + 1 < S), st2 = (s + 2 < S);

    // ---- P0: read A_lo (q0,q2) + B n0-1; stage A_hi(s+1) -> other buf ----
    #pragma unroll
    for (int mm = 0; mm < 4; mm++)
      #pragma unroll
      for (int ks = 0; ks < 2; ks++)
        a[mm][ks] = ldfrag(Ab + mm * 2048 + ardo[ks]);
    #pragma unroll
    for (int nn = 0; nn < 2; nn++)
      #pragma unroll
      for (int ks = 0; ks < 2; ks++)
        bfr[nn][ks] = ldfrag(Bb + nn * 2048 + brdo[ks]);
    if (st1){ STA(AgM, 1, km, cur ^ 1); STA(AgM, 3, km, cur ^ 1); }
    __builtin_amdgcn_s_barrier();
    phase_mfma<0, 0>(acc, a, bfr);
    __builtin_amdgcn_s_barrier();

    // ---- P1: read B n2-3; stage A_lo(s+2) -> this buf ----
    #pragma unroll
    for (int nn = 2; nn < 4; nn++)
      #pragma unroll
      for (int ks = 0; ks < 2; ks++)
        bfr[nn][ks] = ldfrag(Bb + nn * 2048 + brdo[ks]);
    if (st2){ STA(AgP, 0, kp, cur); STA(AgP, 2, kp, cur); }
    __builtin_amdgcn_s_barrier();
    phase_mfma<0, 2>(acc, a, bfr);
    __builtin_amdgcn_s_barrier();

    // ---- P2: read A_hi (q1,q3); stage B q0,q1 (s+2) ----
    #pragma unroll
    for (int mm = 0; mm < 4; mm++)
      #pragma unroll
      for (int ks = 0; ks < 2; ks++)
        a[mm][ks] = ldfrag(Ab + (4 + mm) * 2048 + ardo[ks]);
    if (st2){ STB(BgP, 0, kp, cur); STB(BgP, 1, kp, cur); }
    __builtin_amdgcn_s_barrier();
    phase_mfma<4, 0>(acc, a, bfr);
    __builtin_amdgcn_s_barrier();

    // ---- P3: stage B q2,q3 (s+2); counted vmcnt ----
    if (st2){ STB(BgP, 2, kp, cur); STB(BgP, 3, kp, cur); }
    if (s < S - 2) asm volatile("s_waitcnt vmcnt(6)" ::: "memory");
    else           asm volatile("s_waitcnt vmcnt(0)" ::: "memory");
    __builtin_amdgcn_s_barrier();
    phase_mfma<4, 2>(acc, a, bfr);
    __builtin_amdgcn_s_barrier();

    // ---- cursor advance + epilogue at tile boundary ----
    if (++km == NT){ km = 0; if (++jm < TPB) AgM = abase(lin0 + jm); }
    if (++kp == NT){ kp = 0; if (++jp < TPB){ AgP = abase(lin0 + jp); BgP = bbase(lin0 + jp); } }
    if (++kk == NT){
      kk = 0;
      #pragma unroll
      for (int m = 0; m < 8; m++){
        #pragma unroll
        for (int n = 0; n < 4; n++){
          int gr0 = row0 + wr * 128 + m * 16 + l4 * 4;
          int gc  = col0 + wc * 64 + n * 16 + l15;
          float bcol = BIAS ? (jj == 0 ? bc0[n] : bc1[n]) : 0.f;
          #pragma unroll
          for (int j = 0; j < 4; j++){
            float vv = acc[m][n][j] + bcol;
            int gr = gr0 + j;
            if (OUTF32) ((float*)C)[zbC * sC + (size_t)gr * ldc + gc] = vv;
            else        ((u16*) C)[zbC * sC + (size_t)gr * ldc + gc] = f2bf(vv);
          }
          acc[m][n] = (f32x4){0.f, 0.f, 0.f, 0.f};
        }
      }
      if (++jj < TPB){
        tcoord(lin0 + jj, tx, ty, tz);
        row0 = tx * 256; col0 = ty * 256; zbC = tz;
      }
    }
  }
#undef STA
#undef STB
}

extern "C" void kernel_launch(void* const* d_in, const int* in_sizes, int n_in,
                              void* d_out, int out_size, void* d_ws, size_t ws_size,
                              hipStream_t stream){
  const float* q  = (const float*)d_in[0];
  const float* k  = (const float*)d_in[1];
  const float* v  = (const float*)d_in[2];
  const float* Wq = (const float*)d_in[3];
  const float* bq = (const float*)d_in[4];
  const float* Wk = (const float*)d_in[5];
  const float* bk = (const float*)d_in[6];
  const float* Wv = (const float*)d_in[7];
  const float* bv = (const float*)d_in[8];
  const float* Wo = (const float*)d_in[9];
  const float* bo = (const float*)d_in[10];

  char* ws = (char*)d_ws;
  const size_t MB = (size_t)1 << 20;
  u16* Wqt = (u16*)(ws + 0 * MB);
  u16* Wkt = (u16*)(ws + 2 * MB);
  u16* Wvt = (u16*)(ws + 4 * MB);
  u16* Wot = (u16*)(ws + 6 * MB);
  u16* Qp  = (u16*)(ws + 8 * MB);    // [32768][1024] bf16
  u16* Kp  = (u16*)(ws + 72 * MB);   // [32768][1024] bf16
  u16* Vt  = (u16*)(ws + 136 * MB);  // [16][1024][2048] bf16
  u16* S   = (u16*)(ws + 200 * MB);  // [16][2048][2048] bf16 (P in-place)
  u16* O   = (u16*)(ws + 328 * MB);  // [32768][1024] bf16
  u16* X   = (u16*)(ws + 200 * MB);  // bf16 staging for q/k/v (dead before S written)
  float* out = (float*)d_out;

  dim3 wb(32, 8);
  wcast<<<dim3(32, 32), wb, 0, stream>>>(Wq, 1.f / 32.f, Wqt);  // fold 1/sqrt(D)
  wcast<<<dim3(32, 32), wb, 0, stream>>>(Wk, 1.f, Wkt);
  wcast<<<dim3(32, 32), wb, 0, stream>>>(Wv, 1.f, Wvt);
  wcast<<<dim3(32, 32), wb, 0, stream>>>(Wo, 1.f, Wot);

  const int n8 = 16 * 2048 * 1024 / 8;

  // Q' = (q @ Wq + bq)/32
  castbf<<<dim3(2048), 256, 0, stream>>>(q, X, n8);
  gemm8<1,0><<<dim3(256), 512, 0, stream>>>(X, Wqt, Qp, bq, 1.f/32.f,
      16, 0, 0, 0, 1024, 1024, 1024, 128, 512, 2);
  // K' = k @ Wk + bk
  castbf<<<dim3(2048), 256, 0, stream>>>(k, X, n8);
  gemm8<1,0><<<dim3(256), 512, 0, stream>>>(X, Wkt, Kp, bk, 1.f,
      16, 0, 0, 0, 1024, 1024, 1024, 128, 512, 2);
  // Vt[b][d][kv] = (v @ Wv)^T  (bv folded into PV epilogue: softmax rows sum to 1)
  castbf<<<dim3(2048), 256, 0, stream>>>(v, X, n8);
  gemm8<0,0><<<dim3(256), 512, 0, stream>>>(Wvt, X, Vt, nullptr, 0.f,
      16, 0, 2048LL * 1024, 1024LL * 2048, 1024, 1024, 2048, 4, 32, 2);
  // S[b] = Qp[b] @ Kp[b]^T
  gemm8<0,0><<<dim3(256), 512, 0, stream>>>(Qp, Kp, S, nullptr, 0.f,
      16, 2048LL * 1024, 2048LL * 1024, 2048LL * 2048, 1024, 1024, 2048, 8, 64, 4);
  // P = softmax(S) in place
  softmax_rows<<<dim3(32768), 256, 0, stream>>>(S);
  // O[b] = P[b] @ Vt[b]^T + bv
  gemm8<1,0><<<dim3(256), 512, 0, stream>>>(S, Vt, O, bv, 1.f,
      32, 2048LL * 2048, 1024LL * 2048, 2048LL * 1024, 2048, 2048, 1024, 8, 32, 2);
  // out = O @ Wo + bo (fp32 out)
  gemm8<1,1><<<dim3(256), 512, 0, stream>>>(O, Wot, out, bo, 1.f,
      16, 0, 0, 0, 1024, 1024, 1024, 128, 512, 2);
}